// Round 1
// baseline (608.700 us; speedup 1.0000x reference)
//
#include <hip/hip_runtime.h>
#include <stdint.h>

typedef unsigned short ushort_t;
typedef __bf16 bf16x8 __attribute__((ext_vector_type(8)));
typedef float f32x4 __attribute__((ext_vector_type(4)));

// ---- bf16 helpers (RTNE) ----
__device__ __forceinline__ ushort_t f2bf(float x) {
  uint32_t u = __builtin_bit_cast(uint32_t, x);
  u += 0x7fffu + ((u >> 16) & 1u);
  return (ushort_t)(u >> 16);
}
__device__ __forceinline__ float bf2f(ushort_t h) {
  return __builtin_bit_cast(float, (uint32_t)h << 16);
}

// ---- async global->LDS, 16B per lane ----
__device__ __forceinline__ void gload_lds16(const void* g, uint32_t lds_addr) {
  __builtin_amdgcn_global_load_lds(
      (const __attribute__((address_space(1))) void*)(uintptr_t)g,
      (__attribute__((address_space(3))) void*)(uintptr_t)lds_addr,
      16, 0, 0);
}

// ---- elementwise fp32 -> (hi,lo) bf16 split; 4 elems/thread, exact grid ----
__global__ __launch_bounds__(256) void cvt_hilo(const float* __restrict__ x,
                                                ushort_t* __restrict__ hi,
                                                ushort_t* __restrict__ lo) {
  size_t i = (size_t)blockIdx.x * 256 + threadIdx.x;
  float4 v = ((const float4*)x)[i];
  float f[4] = {v.x, v.y, v.z, v.w};
  ushort_t h[4], L[4];
#pragma unroll
  for (int j = 0; j < 4; j++) {
    h[j] = f2bf(f[j]);
    L[j] = f2bf(f[j] - bf2f(h[j]));
  }
  uint2 hv, lv;
  hv.x = (uint32_t)h[0] | ((uint32_t)h[1] << 16);
  hv.y = (uint32_t)h[2] | ((uint32_t)h[3] << 16);
  lv.x = (uint32_t)L[0] | ((uint32_t)L[1] << 16);
  lv.y = (uint32_t)L[2] | ((uint32_t)L[3] << 16);
  ((uint2*)hi)[i] = hv;
  ((uint2*)lo)[i] = lv;
}

// ---- K [2048][1024] -> KT hi/lo [1024][2048] (per batch, blockIdx.z) ----
__global__ __launch_bounds__(256) void cvt_T(const float* __restrict__ K,
                                             ushort_t* __restrict__ thi,
                                             ushort_t* __restrict__ tlo) {
  __shared__ uint32_t tile[32][33];
  const int b = blockIdx.z;
  const float* Kb = K + (size_t)b * 2048 * 1024;
  const int d0 = blockIdx.x * 32, t0 = blockIdx.y * 32;
  const int tx = threadIdx.x & 31, ty = threadIdx.x >> 5;
#pragma unroll
  for (int r = 0; r < 4; r++) {
    int row = ty + r * 8;
    float v = Kb[(size_t)(t0 + row) * 1024 + d0 + tx];
    ushort_t h = f2bf(v);
    ushort_t L = f2bf(v - bf2f(h));
    tile[row][tx] = ((uint32_t)h << 16) | (uint32_t)L;
  }
  __syncthreads();
  size_t ob = (size_t)b * 1024 * 2048;
#pragma unroll
  for (int r = 0; r < 4; r++) {
    int d = ty + r * 8;
    uint32_t v = tile[tx][d];
    size_t o = ob + (size_t)(d0 + d) * 2048 + (t0 + tx);
    thi[o] = (ushort_t)(v >> 16);
    tlo[o] = (ushort_t)(v & 0xffffu);
  }
}

// ---- row softmax: E fp32 [rows][2048] -> P bf16 [rows][2048] ----
__global__ __launch_bounds__(256) void softmax_rows(const float* __restrict__ E,
                                                    ushort_t* __restrict__ P) {
  const size_t row = blockIdx.x;
  const float* e = E + row * 2048;
  const int t = threadIdx.x;
  float4 a = ((const float4*)e)[t * 2];
  float4 b = ((const float4*)e)[t * 2 + 1];
  float f[8] = {a.x, a.y, a.z, a.w, b.x, b.y, b.z, b.w};
  float m = f[0];
#pragma unroll
  for (int j = 1; j < 8; j++) m = fmaxf(m, f[j]);
#pragma unroll
  for (int off = 32; off > 0; off >>= 1) m = fmaxf(m, __shfl_down(m, off));
  __shared__ float redm[4], reds[4];
  if ((t & 63) == 0) redm[t >> 6] = m;
  __syncthreads();
  m = fmaxf(fmaxf(redm[0], redm[1]), fmaxf(redm[2], redm[3]));
  float ex[8];
  float s = 0.f;
#pragma unroll
  for (int j = 0; j < 8; j++) { ex[j] = expf(f[j] - m); s += ex[j]; }
#pragma unroll
  for (int off = 32; off > 0; off >>= 1) s += __shfl_down(s, off);
  if ((t & 63) == 0) reds[t >> 6] = s;
  __syncthreads();
  s = reds[0] + reds[1] + reds[2] + reds[3];
  float inv = 1.0f / s;
  uint4 o;
  uint32_t wv[4];
#pragma unroll
  for (int j = 0; j < 4; j++) {
    uint32_t lo16 = f2bf(ex[2 * j] * inv);
    uint32_t hi16 = f2bf(ex[2 * j + 1] * inv);
    wv[j] = lo16 | (hi16 << 16);
  }
  o.x = wv[0]; o.y = wv[1]; o.z = wv[2]; o.w = wv[3];
  ((uint4*)(P + row * 2048))[t] = o;
}

// ---- BT GEMM: C[m][n] = sum_k A[m][k] * Bt[n][k], all k-contiguous bf16 ----
// SPLIT_A=true : 3 products (Ahi*Bhi + Ahi*Blo + Alo*Bhi)   [GEMM1: E = Q.K^T]
// SPLIT_A=false: 2 products (A*Bhi + A*Blo)                 [GEMM2: O = P.K]
// 128x128 tile, 4 waves in 2x2, 16x16x32 bf16 MFMA, BK=32, async staging,
// XOR swizzle of 16B quads (q ^= (row>>1)&3) keeps ds_read_b128 at 2-way (free).
template <bool SPLIT_A>
__global__ __launch_bounds__(256) void gemm_bt(
    const ushort_t* __restrict__ A0, const ushort_t* __restrict__ A1,
    const ushort_t* __restrict__ B0, const ushort_t* __restrict__ B1,
    float* __restrict__ C, int Kdim, int ldc, long sA, long sB, long sC) {
  constexpr int NBUF = SPLIT_A ? 4 : 3;
  constexpr int NA = SPLIT_A ? 2 : 1;
  __shared__ ushort_t lds[NBUF * 4096];  // NBUF buffers of 128x32 bf16 (8KB)
  const int tid = threadIdx.x;
  const int w = tid >> 6, l = tid & 63;
  const int bz = blockIdx.z;
  const int rowA = blockIdx.y * 128, rowB = blockIdx.x * 128;

  const ushort_t* bases[4];
  int rbase[4];
  if constexpr (SPLIT_A) {
    bases[0] = A0 + bz * sA; bases[1] = A1 + bz * sA;
    bases[2] = B0 + bz * sB; bases[3] = B1 + bz * sB;
    rbase[0] = rowA; rbase[1] = rowA; rbase[2] = rowB; rbase[3] = rowB;
  } else {
    bases[0] = A0 + bz * sA;
    bases[1] = B0 + bz * sB; bases[2] = B1 + bz * sB;
    rbase[0] = rowA; rbase[1] = rowB; rbase[2] = rowB;
    bases[3] = nullptr; rbase[3] = 0;
  }
  // staging: 1KB chunks (16 rows x 64B); 8 chunks/buffer; 2*NBUF insts/wave
  const ushort_t* gp[2 * NBUF];
  uint32_t lpo[2 * NBUF];
#pragma unroll
  for (int i = 0; i < 2 * NBUF; i++) {
    int gc = w * 2 * NBUF + i;
    int buf = gc >> 3, c = gc & 7;
    int row = c * 16 + (l >> 2);
    int q = (l & 3) ^ ((row >> 1) & 3);  // fetch the quad that belongs in this phys slot
    gp[i] = bases[buf] + (size_t)(rbase[buf] + row) * Kdim + q * 8;
    lpo[i] = (uint32_t)(uintptr_t)(lds + buf * 4096 + c * 512 + l * 8);
  }
  f32x4 acc[4][4];
  const f32x4 zero = {0.f, 0.f, 0.f, 0.f};
#pragma unroll
  for (int mt = 0; mt < 4; mt++)
#pragma unroll
    for (int nt = 0; nt < 4; nt++) acc[mt][nt] = zero;

  const int wm = w & 1, wn = w >> 1, q4 = l >> 4, rl = l & 15;
  for (int k0 = 0; k0 < Kdim; k0 += 32) {
    __syncthreads();
#pragma unroll
    for (int i = 0; i < 2 * NBUF; i++) gload_lds16(gp[i], lpo[i]);
#pragma unroll
    for (int i = 0; i < 2 * NBUF; i++) gp[i] += 32;
    __syncthreads();
    bf16x8 af[NA][4];
    bf16x8 bfr[2][4];
#pragma unroll
    for (int mt = 0; mt < 4; mt++) {
      int row = wm * 64 + mt * 16 + rl;
      int off = row * 32 + ((q4 ^ ((row >> 1) & 3)) << 3);
      af[0][mt] = *(const bf16x8*)(lds + off);
      if constexpr (SPLIT_A) af[1][mt] = *(const bf16x8*)(lds + 4096 + off);
    }
    constexpr int BOFF = NA * 4096;
#pragma unroll
    for (int nt = 0; nt < 4; nt++) {
      int row = wn * 64 + nt * 16 + rl;
      int off = row * 32 + ((q4 ^ ((row >> 1) & 3)) << 3);
      bfr[0][nt] = *(const bf16x8*)(lds + BOFF + off);
      bfr[1][nt] = *(const bf16x8*)(lds + BOFF + 4096 + off);
    }
#pragma unroll
    for (int mt = 0; mt < 4; mt++)
#pragma unroll
      for (int nt = 0; nt < 4; nt++) {
        acc[mt][nt] = __builtin_amdgcn_mfma_f32_16x16x32_bf16(af[0][mt], bfr[0][nt], acc[mt][nt], 0, 0, 0);
        acc[mt][nt] = __builtin_amdgcn_mfma_f32_16x16x32_bf16(af[0][mt], bfr[1][nt], acc[mt][nt], 0, 0, 0);
        if constexpr (SPLIT_A)
          acc[mt][nt] = __builtin_amdgcn_mfma_f32_16x16x32_bf16(af[1][mt], bfr[0][nt], acc[mt][nt], 0, 0, 0);
      }
  }
  // C/D layout (verified m89/m91): col = lane&15, row = (lane>>4)*4 + reg
  float* Cb = C + (size_t)bz * sC + (size_t)rowA * ldc + rowB;
#pragma unroll
  for (int mt = 0; mt < 4; mt++)
#pragma unroll
    for (int nt = 0; nt < 4; nt++)
#pragma unroll
      for (int r = 0; r < 4; r++)
        Cb[(size_t)(wm * 64 + mt * 16 + q4 * 4 + r) * ldc + (wn * 64 + nt * 16 + rl)] =
            acc[mt][nt][r];
}

extern "C" void kernel_launch(void* const* d_in, const int* in_sizes, int n_in,
                              void* d_out, int out_size, void* d_ws, size_t ws_size,
                              hipStream_t stream) {
  (void)in_sizes; (void)n_in; (void)out_size;
  const float* Q = (const float*)d_in[0];
  const float* K = (const float*)d_in[1];
  float* O = (float*)d_out;
  const int Btot = 8, Tq = 2048, Tk = 2048, D = 1024;
  // ws per batch: 6 bf16 arrays (Qhi/Qlo/Khi/Klo/KThi/KTlo, 4MB each) + E 16MB + P 8MB = 48MB
  const size_t perb = 48ull << 20;
  int NB = 8;
  while (NB > 1 && (size_t)NB * perb > ws_size) NB >>= 1;

  char* p = (char*)d_ws;
  const size_t qd = (size_t)NB * Tq * D;
  const size_t kd = (size_t)NB * Tk * D;
  const size_t ee = (size_t)NB * Tq * Tk;
  ushort_t* Qhi = (ushort_t*)p; p += qd * 2;
  ushort_t* Qlo = (ushort_t*)p; p += qd * 2;
  ushort_t* Khi = (ushort_t*)p; p += kd * 2;
  ushort_t* Klo = (ushort_t*)p; p += kd * 2;
  ushort_t* KThi = (ushort_t*)p; p += kd * 2;
  ushort_t* KTlo = (ushort_t*)p; p += kd * 2;
  float* E = (float*)p; p += ee * 4;
  ushort_t* P = (ushort_t*)p; p += ee * 2;

  for (int c = 0; c < Btot / NB; c++) {
    const float* Qc = Q + (size_t)c * qd;
    const float* Kc = K + (size_t)c * kd;
    float* Oc = O + (size_t)c * qd;
    cvt_hilo<<<dim3(NB * 2048), 256, 0, stream>>>(Qc, Qhi, Qlo);
    cvt_hilo<<<dim3(NB * 2048), 256, 0, stream>>>(Kc, Khi, Klo);
    cvt_T<<<dim3(32, 64, NB), 256, 0, stream>>>(Kc, KThi, KTlo);
    // E[b][q][t] = sum_d Q[q][d] K[t][d]
    gemm_bt<true><<<dim3(16, 16, NB), 256, 0, stream>>>(
        Qhi, Qlo, Khi, Klo, E, 1024, 2048, (long)Tq * D, (long)Tk * D, (long)Tq * Tk);
    softmax_rows<<<dim3(NB * Tq), 256, 0, stream>>>(E, P);
    // O[b][q][d] = sum_t P[q][t] KT[d][t]
    gemm_bt<false><<<dim3(8, 16, NB), 256, 0, stream>>>(
        P, nullptr, KThi, KTlo, Oc, 2048, 1024, (long)Tq * Tk, (long)D * Tk, (long)Tq * D);
  }
}

// Round 2
// 565.630 us; speedup vs baseline: 1.0761x; 1.0761x over previous
//
#include <hip/hip_runtime.h>
#include <stdint.h>

typedef unsigned short ushort_t;
typedef __bf16 bf16x8 __attribute__((ext_vector_type(8)));
typedef float f32x4 __attribute__((ext_vector_type(4)));

// ---- bf16 helpers (RTNE) ----
__device__ __forceinline__ ushort_t f2bf(float x) {
  uint32_t u = __builtin_bit_cast(uint32_t, x);
  u += 0x7fffu + ((u >> 16) & 1u);
  return (ushort_t)(u >> 16);
}
__device__ __forceinline__ float bf2f(ushort_t h) {
  return __builtin_bit_cast(float, (uint32_t)h << 16);
}

// ---- async global->LDS, 16B per lane ----
__device__ __forceinline__ void gload_lds16(const void* g, uint32_t lds_addr) {
  __builtin_amdgcn_global_load_lds(
      (const __attribute__((address_space(1))) void*)(uintptr_t)g,
      (__attribute__((address_space(3))) void*)(uintptr_t)lds_addr,
      16, 0, 0);
}

// ---- Q: fp32 -> (hi,lo) bf16 split; 4 elems/thread ----
__global__ __launch_bounds__(256) void cvt_hilo(const float* __restrict__ x,
                                                ushort_t* __restrict__ hi,
                                                ushort_t* __restrict__ lo) {
  size_t i = (size_t)blockIdx.x * 256 + threadIdx.x;
  float4 v = ((const float4*)x)[i];
  float f[4] = {v.x, v.y, v.z, v.w};
  ushort_t h[4], L[4];
#pragma unroll
  for (int j = 0; j < 4; j++) {
    h[j] = f2bf(f[j]);
    L[j] = f2bf(f[j] - bf2f(h[j]));
  }
  uint2 hv, lv;
  hv.x = (uint32_t)h[0] | ((uint32_t)h[1] << 16);
  hv.y = (uint32_t)h[2] | ((uint32_t)h[3] << 16);
  lv.x = (uint32_t)L[0] | ((uint32_t)L[1] << 16);
  lv.y = (uint32_t)L[2] | ((uint32_t)L[3] << 16);
  ((uint2*)hi)[i] = hv;
  ((uint2*)lo)[i] = lv;
}

// ---- K: one pass -> Khi/Klo [t][d] + KThi/KTlo [d][t], all 16B stores ----
// tile: 64 t x 32 d per block
__global__ __launch_bounds__(256) void cvt_k(const float* __restrict__ K,
                                             ushort_t* __restrict__ khi,
                                             ushort_t* __restrict__ klo,
                                             ushort_t* __restrict__ thi,
                                             ushort_t* __restrict__ tlo) {
  __shared__ uint32_t tile[64][33];  // (hi<<16)|lo
  const int b = blockIdx.z;
  const int d0 = blockIdx.x * 32, t0 = blockIdx.y * 64;
  const int tid = threadIdx.x;
  const float* Kb = K + (size_t)b * 2048 * 1024;
  {
    const int t = tid >> 2, d8 = (tid & 3) * 8;
    const float* src = Kb + (size_t)(t0 + t) * 1024 + d0 + d8;
    float4 v0 = ((const float4*)src)[0];
    float4 v1 = ((const float4*)src)[1];
    float f[8] = {v0.x, v0.y, v0.z, v0.w, v1.x, v1.y, v1.z, v1.w};
    uint32_t hh[8], ll[8];
#pragma unroll
    for (int j = 0; j < 8; j++) {
      ushort_t h = f2bf(f[j]);
      ushort_t L = f2bf(f[j] - bf2f(h));
      hh[j] = h; ll[j] = L;
      tile[t][d8 + j] = ((uint32_t)h << 16) | (uint32_t)L;
    }
    uint4 H, Lo;
    H.x = hh[0] | (hh[1] << 16); H.y = hh[2] | (hh[3] << 16);
    H.z = hh[4] | (hh[5] << 16); H.w = hh[6] | (hh[7] << 16);
    Lo.x = ll[0] | (ll[1] << 16); Lo.y = ll[2] | (ll[3] << 16);
    Lo.z = ll[4] | (ll[5] << 16); Lo.w = ll[6] | (ll[7] << 16);
    size_t off = (size_t)b * 2048 * 1024 + (size_t)(t0 + t) * 1024 + d0 + d8;
    *(uint4*)(khi + off) = H;
    *(uint4*)(klo + off) = Lo;
  }
  __syncthreads();
  {
    const int d = tid >> 3, tg = tid & 7;
    uint32_t vv[8];
#pragma unroll
    for (int i = 0; i < 8; i++) vv[i] = tile[tg * 8 + i][d];
    uint4 H, Lo;
    H.x = (vv[0] >> 16) | (vv[1] & 0xffff0000u);
    H.y = (vv[2] >> 16) | (vv[3] & 0xffff0000u);
    H.z = (vv[4] >> 16) | (vv[5] & 0xffff0000u);
    H.w = (vv[6] >> 16) | (vv[7] & 0xffff0000u);
    Lo.x = (vv[0] & 0xffffu) | (vv[1] << 16);
    Lo.y = (vv[2] & 0xffffu) | (vv[3] << 16);
    Lo.z = (vv[4] & 0xffffu) | (vv[5] << 16);
    Lo.w = (vv[6] & 0xffffu) | (vv[7] << 16);
    size_t off = (size_t)b * 1024 * 2048 + (size_t)(d0 + d) * 2048 + t0 + tg * 8;
    *(uint4*)(thi + off) = H;
    *(uint4*)(tlo + off) = Lo;
  }
}

// ---- row softmax: E fp32 [rows][2048] -> P bf16 [rows][2048] ----
__global__ __launch_bounds__(256) void softmax_rows(const float* __restrict__ E,
                                                    ushort_t* __restrict__ P) {
  const size_t row = blockIdx.x;
  const float* e = E + row * 2048;
  const int t = threadIdx.x;
  float4 a = ((const float4*)e)[t * 2];
  float4 b = ((const float4*)e)[t * 2 + 1];
  float f[8] = {a.x, a.y, a.z, a.w, b.x, b.y, b.z, b.w};
  float m = f[0];
#pragma unroll
  for (int j = 1; j < 8; j++) m = fmaxf(m, f[j]);
#pragma unroll
  for (int off = 32; off > 0; off >>= 1) m = fmaxf(m, __shfl_down(m, off));
  __shared__ float redm[4], reds[4];
  if ((t & 63) == 0) redm[t >> 6] = m;
  __syncthreads();
  m = fmaxf(fmaxf(redm[0], redm[1]), fmaxf(redm[2], redm[3]));
  float ex[8];
  float s = 0.f;
#pragma unroll
  for (int j = 0; j < 8; j++) { ex[j] = __expf(f[j] - m); s += ex[j]; }
#pragma unroll
  for (int off = 32; off > 0; off >>= 1) s += __shfl_down(s, off);
  if ((t & 63) == 0) reds[t >> 6] = s;
  __syncthreads();
  s = reds[0] + reds[1] + reds[2] + reds[3];
  float inv = 1.0f / s;
  uint4 o;
  uint32_t wv[4];
#pragma unroll
  for (int j = 0; j < 4; j++) {
    uint32_t lo16 = f2bf(ex[2 * j] * inv);
    uint32_t hi16 = f2bf(ex[2 * j + 1] * inv);
    wv[j] = lo16 | (hi16 << 16);
  }
  o.x = wv[0]; o.y = wv[1]; o.z = wv[2]; o.w = wv[3];
  ((uint4*)(P + row * 2048))[t] = o;
}

// ---- GEMM1: E = Qhi.Khi^T + Qhi.Klo^T + Qlo.Khi^T ; BK=32, 128x128 tile ----
__global__ __launch_bounds__(256) void gemm1_bt(
    const ushort_t* __restrict__ A0, const ushort_t* __restrict__ A1,
    const ushort_t* __restrict__ B0, const ushort_t* __restrict__ B1,
    float* __restrict__ C, int Kdim, int ldc, long sA, long sB, long sC) {
  __shared__ ushort_t lds[4 * 4096];  // 4 buffers of 128x32 bf16 (8KB)
  const int tid = threadIdx.x;
  const int w = tid >> 6, l = tid & 63;
  const int bz = blockIdx.z;
  const int rowA = blockIdx.y * 128, rowB = blockIdx.x * 128;

  const ushort_t* bases[4] = {A0 + bz * sA, A1 + bz * sA, B0 + bz * sB, B1 + bz * sB};
  const int rbase[4] = {rowA, rowA, rowB, rowB};
  const ushort_t* gp[8];
  uint32_t lpo[8];
#pragma unroll
  for (int i = 0; i < 8; i++) {
    int gc = w * 8 + i;
    int buf = gc >> 3, c = gc & 7;
    int row = c * 16 + (l >> 2);
    int q = (l & 3) ^ ((row >> 1) & 3);
    gp[i] = bases[buf] + (size_t)(rbase[buf] + row) * Kdim + q * 8;
    lpo[i] = (uint32_t)(uintptr_t)(lds + buf * 4096 + c * 512 + l * 8);
  }
  f32x4 acc[4][4];
  const f32x4 zero = {0.f, 0.f, 0.f, 0.f};
#pragma unroll
  for (int mt = 0; mt < 4; mt++)
#pragma unroll
    for (int nt = 0; nt < 4; nt++) acc[mt][nt] = zero;

  const int wm = w & 1, wn = w >> 1, q4 = l >> 4, rl = l & 15;
  for (int k0 = 0; k0 < Kdim; k0 += 32) {
    __syncthreads();
#pragma unroll
    for (int i = 0; i < 8; i++) gload_lds16(gp[i], lpo[i]);
#pragma unroll
    for (int i = 0; i < 8; i++) gp[i] += 32;
    __syncthreads();
    bf16x8 af[2][4];
    bf16x8 bfr[2][4];
#pragma unroll
    for (int mt = 0; mt < 4; mt++) {
      int row = wm * 64 + mt * 16 + rl;
      int off = row * 32 + ((q4 ^ ((row >> 1) & 3)) << 3);
      af[0][mt] = *(const bf16x8*)(lds + off);
      af[1][mt] = *(const bf16x8*)(lds + 4096 + off);
    }
#pragma unroll
    for (int nt = 0; nt < 4; nt++) {
      int row = wn * 64 + nt * 16 + rl;
      int off = row * 32 + ((q4 ^ ((row >> 1) & 3)) << 3);
      bfr[0][nt] = *(const bf16x8*)(lds + 8192 + off);
      bfr[1][nt] = *(const bf16x8*)(lds + 12288 + off);
    }
#pragma unroll
    for (int mt = 0; mt < 4; mt++)
#pragma unroll
      for (int nt = 0; nt < 4; nt++) {
        acc[mt][nt] = __builtin_amdgcn_mfma_f32_16x16x32_bf16(af[0][mt], bfr[0][nt], acc[mt][nt], 0, 0, 0);
        acc[mt][nt] = __builtin_amdgcn_mfma_f32_16x16x32_bf16(af[0][mt], bfr[1][nt], acc[mt][nt], 0, 0, 0);
        acc[mt][nt] = __builtin_amdgcn_mfma_f32_16x16x32_bf16(af[1][mt], bfr[0][nt], acc[mt][nt], 0, 0, 0);
      }
  }
  float* Cb = C + (size_t)bz * sC + (size_t)rowA * ldc + rowB;
#pragma unroll
  for (int mt = 0; mt < 4; mt++)
#pragma unroll
    for (int nt = 0; nt < 4; nt++)
#pragma unroll
      for (int r = 0; r < 4; r++)
        Cb[(size_t)(wm * 64 + mt * 16 + q4 * 4 + r) * ldc + (wn * 64 + nt * 16 + rl)] =
            acc[mt][nt][r];
}

// ---- GEMM2: O = P.KThi^T + P.KTlo^T ; BK=64, 128x128 tile, 48KB LDS ----
// LDS buffers: A(P) at 0, B0 at 8192, B1 at 16384 (ushort units; 16KB each).
// Row = 128B (64 bf16) = 8 quads; physical quad = logical quad ^ (row&7).
__global__ __launch_bounds__(256) void gemm2_bt(
    const ushort_t* __restrict__ A0,
    const ushort_t* __restrict__ B0, const ushort_t* __restrict__ B1,
    float* __restrict__ C, int Kdim, int ldc, long sA, long sB, long sC) {
  __shared__ ushort_t lds[3 * 8192];
  const int tid = threadIdx.x;
  const int w = tid >> 6, l = tid & 63;
  const int bz = blockIdx.z;
  const int rowA = blockIdx.y * 128, rowB = blockIdx.x * 128;

  const ushort_t* bases[3] = {A0 + bz * sA, B0 + bz * sB, B1 + bz * sB};
  const int rbase[3] = {rowA, rowB, rowB};
  // 48 chunks of 1KB (8 rows x 128B); 12 per wave
  const ushort_t* gp[12];
  uint32_t lpo[12];
#pragma unroll
  for (int i = 0; i < 12; i++) {
    int gc = w * 12 + i;
    int buf = gc >> 4, c = gc & 15;
    int row = c * 8 + (l >> 3);
    int q = (l & 7) ^ (l >> 3);  // row&7 == l>>3 since c*8 is 8-aligned
    gp[i] = bases[buf] + (size_t)(rbase[buf] + row) * Kdim + q * 8;
    lpo[i] = (uint32_t)(uintptr_t)(lds + buf * 8192 + c * 512 + l * 8);
  }
  f32x4 acc[4][4];
  const f32x4 zero = {0.f, 0.f, 0.f, 0.f};
#pragma unroll
  for (int mt = 0; mt < 4; mt++)
#pragma unroll
    for (int nt = 0; nt < 4; nt++) acc[mt][nt] = zero;

  const int wm = w & 1, wn = w >> 1, q4 = l >> 4, rl = l & 15;
  for (int k0 = 0; k0 < Kdim; k0 += 64) {
    __syncthreads();
#pragma unroll
    for (int i = 0; i < 12; i++) gload_lds16(gp[i], lpo[i]);
#pragma unroll
    for (int i = 0; i < 12; i++) gp[i] += 64;
    __syncthreads();
#pragma unroll
    for (int kh = 0; kh < 2; kh++) {
      bf16x8 af[4];
      bf16x8 bfr[2][4];
#pragma unroll
      for (int mt = 0; mt < 4; mt++) {
        int row = wm * 64 + mt * 16 + rl;
        int off = row * 64 + (((kh * 4 + q4) ^ (row & 7)) << 3);
        af[mt] = *(const bf16x8*)(lds + off);
      }
#pragma unroll
      for (int nt = 0; nt < 4; nt++) {
        int row = wn * 64 + nt * 16 + rl;
        int off = row * 64 + (((kh * 4 + q4) ^ (row & 7)) << 3);
        bfr[0][nt] = *(const bf16x8*)(lds + 8192 + off);
        bfr[1][nt] = *(const bf16x8*)(lds + 16384 + off);
      }
#pragma unroll
      for (int mt = 0; mt < 4; mt++)
#pragma unroll
        for (int nt = 0; nt < 4; nt++) {
          acc[mt][nt] = __builtin_amdgcn_mfma_f32_16x16x32_bf16(af[mt], bfr[0][nt], acc[mt][nt], 0, 0, 0);
          acc[mt][nt] = __builtin_amdgcn_mfma_f32_16x16x32_bf16(af[mt], bfr[1][nt], acc[mt][nt], 0, 0, 0);
        }
    }
  }
  float* Cb = C + (size_t)bz * sC + (size_t)rowA * ldc + rowB;
#pragma unroll
  for (int mt = 0; mt < 4; mt++)
#pragma unroll
    for (int nt = 0; nt < 4; nt++)
#pragma unroll
      for (int r = 0; r < 4; r++)
        Cb[(size_t)(wm * 64 + mt * 16 + q4 * 4 + r) * ldc + (wn * 64 + nt * 16 + rl)] =
            acc[mt][nt][r];
}

extern "C" void kernel_launch(void* const* d_in, const int* in_sizes, int n_in,
                              void* d_out, int out_size, void* d_ws, size_t ws_size,
                              hipStream_t stream) {
  (void)in_sizes; (void)n_in; (void)out_size;
  const float* Q = (const float*)d_in[0];
  const float* K = (const float*)d_in[1];
  float* O = (float*)d_out;
  const int Btot = 8, Tq = 2048, Tk = 2048, D = 1024;
  const size_t perb = 48ull << 20;
  int NB = 8;
  while (NB > 1 && (size_t)NB * perb > ws_size) NB >>= 1;

  char* p = (char*)d_ws;
  const size_t qd = (size_t)NB * Tq * D;
  const size_t kd = (size_t)NB * Tk * D;
  const size_t ee = (size_t)NB * Tq * Tk;
  ushort_t* Qhi = (ushort_t*)p; p += qd * 2;
  ushort_t* Qlo = (ushort_t*)p; p += qd * 2;
  ushort_t* Khi = (ushort_t*)p; p += kd * 2;
  ushort_t* Klo = (ushort_t*)p; p += kd * 2;
  ushort_t* KThi = (ushort_t*)p; p += kd * 2;
  ushort_t* KTlo = (ushort_t*)p; p += kd * 2;
  float* E = (float*)p; p += ee * 4;
  ushort_t* P = (ushort_t*)p; p += ee * 2;

  for (int c = 0; c < Btot / NB; c++) {
    const float* Qc = Q + (size_t)c * qd;
    const float* Kc = K + (size_t)c * kd;
    float* Oc = O + (size_t)c * qd;
    cvt_hilo<<<dim3(NB * 2048), 256, 0, stream>>>(Qc, Qhi, Qlo);
    cvt_k<<<dim3(32, 32, NB), 256, 0, stream>>>(Kc, Khi, Klo, KThi, KTlo);
    gemm1_bt<<<dim3(16, 16, NB), 256, 0, stream>>>(
        Qhi, Qlo, Khi, Klo, E, 1024, 2048, (long)Tq * D, (long)Tk * D, (long)Tq * Tk);
    softmax_rows<<<dim3(NB * Tq), 256, 0, stream>>>(E, P);
    gemm2_bt<<<dim3(8, 16, NB), 256, 0, stream>>>(
        P, KThi, KTlo, Oc, 2048, 1024, (long)Tq * Tk, (long)D * Tk, (long)Tq * D);
  }
}

// Round 3
// 561.331 us; speedup vs baseline: 1.0844x; 1.0077x over previous
//
#include <hip/hip_runtime.h>
#include <stdint.h>

typedef int i32x4 __attribute__((ext_vector_type(4)));
typedef int8_t s8;

// ---- async global->LDS, 16B per lane ----
__device__ __forceinline__ void gload_lds16(const void* g, uint32_t lds_addr) {
  __builtin_amdgcn_global_load_lds(
      (const __attribute__((address_space(1))) void*)(uintptr_t)g,
      (__attribute__((address_space(3))) void*)(uintptr_t)lds_addr,
      16, 0, 0);
}

// ---- 2-level int8 split: x ~= s*(q1 + q2/128), |err| <= s/512 ----
__device__ __forceinline__ void qsplit(float x, float s, float sinv, float s2inv,
                                       int& q1, int& q2) {
  float a = rintf(x * sinv);
  a = fminf(fmaxf(a, -127.f), 127.f);
  float r = fmaf(a, -s, x);
  float b = fminf(fmaxf(rintf(r * s2inv), -127.f), 127.f);
  q1 = (int)a; q2 = (int)b;
}
__device__ __forceinline__ uint32_t pack4(int b0, int b1, int b2, int b3) {
  return ((uint32_t)(uint8_t)b0) | ((uint32_t)(uint8_t)b1 << 8) |
         ((uint32_t)(uint8_t)b2 << 16) | ((uint32_t)(uint8_t)b3 << 24);
}

#define SQ (8.0f / 127.0f)
#define SQ_INV 15.875f
#define SQ2_INV 2032.0f

// ---- Q: fp32 -> q1,q2 int8; 8 elems/thread ----
__global__ __launch_bounds__(256) void cvt_q_i8(const float* __restrict__ x,
                                                s8* __restrict__ a, s8* __restrict__ b) {
  size_t i = ((size_t)blockIdx.x * 256 + threadIdx.x) * 8;
  float4 v0 = ((const float4*)(x + i))[0];
  float4 v1 = ((const float4*)(x + i))[1];
  float f[8] = {v0.x, v0.y, v0.z, v0.w, v1.x, v1.y, v1.z, v1.w};
  int q1[8], q2[8];
#pragma unroll
  for (int j = 0; j < 8; j++) qsplit(f[j], SQ, SQ_INV, SQ2_INV, q1[j], q2[j]);
  uint2 ua, ub;
  ua.x = pack4(q1[0], q1[1], q1[2], q1[3]); ua.y = pack4(q1[4], q1[5], q1[6], q1[7]);
  ub.x = pack4(q2[0], q2[1], q2[2], q2[3]); ub.y = pack4(q2[4], q2[5], q2[6], q2[7]);
  *(uint2*)(a + i) = ua;
  *(uint2*)(b + i) = ub;
}

// ---- K: one pass -> K1/K2 [t][d] + KT1/KT2 [d][t] int8 ----
__global__ __launch_bounds__(256) void cvt_k_i8(const float* __restrict__ K,
                                                s8* __restrict__ k1, s8* __restrict__ k2,
                                                s8* __restrict__ t1, s8* __restrict__ t2) {
  __shared__ uint32_t tile[64][33];  // low byte q1, next byte q2
  const int b = blockIdx.z;
  const int d0 = blockIdx.x * 32, t0 = blockIdx.y * 64;
  const int tid = threadIdx.x;
  const float* Kb = K + (size_t)b * 2048 * 1024;
  {
    const int t = tid >> 2, d8 = (tid & 3) * 8;
    const float* src = Kb + (size_t)(t0 + t) * 1024 + d0 + d8;
    float4 v0 = ((const float4*)src)[0];
    float4 v1 = ((const float4*)src)[1];
    float f[8] = {v0.x, v0.y, v0.z, v0.w, v1.x, v1.y, v1.z, v1.w};
    int q1[8], q2[8];
#pragma unroll
    for (int j = 0; j < 8; j++) {
      qsplit(f[j], SQ, SQ_INV, SQ2_INV, q1[j], q2[j]);
      tile[t][d8 + j] = ((uint32_t)(uint8_t)q1[j]) | ((uint32_t)(uint8_t)q2[j] << 8);
    }
    uint2 ua, ub;
    ua.x = pack4(q1[0], q1[1], q1[2], q1[3]); ua.y = pack4(q1[4], q1[5], q1[6], q1[7]);
    ub.x = pack4(q2[0], q2[1], q2[2], q2[3]); ub.y = pack4(q2[4], q2[5], q2[6], q2[7]);
    size_t off = (size_t)b * 2048 * 1024 + (size_t)(t0 + t) * 1024 + d0 + d8;
    *(uint2*)(k1 + off) = ua;
    *(uint2*)(k2 + off) = ub;
  }
  __syncthreads();
  {
    const int d = tid >> 3, tg = tid & 7;
    uint32_t v[8];
#pragma unroll
    for (int i = 0; i < 8; i++) v[i] = tile[tg * 8 + i][d];
    uint2 ua, ub;
    ua.x = pack4(v[0], v[1], v[2], v[3]); ua.y = pack4(v[4], v[5], v[6], v[7]);
    ub.x = pack4(v[0] >> 8, v[1] >> 8, v[2] >> 8, v[3] >> 8);
    ub.y = pack4(v[4] >> 8, v[5] >> 8, v[6] >> 8, v[7] >> 8);
    size_t off = (size_t)b * 1024 * 2048 + (size_t)(d0 + d) * 2048 + t0 + tg * 8;
    *(uint2*)(t1 + off) = ua;
    *(uint2*)(t2 + off) = ub;
  }
}

// ---- row softmax: E fp32 [rows][2048] -> P1,P2 int8 (P ~= (p1 + p2/128)/127) ----
__global__ __launch_bounds__(256) void softmax_i8(const float* __restrict__ E,
                                                  s8* __restrict__ P1, s8* __restrict__ P2) {
  const size_t row = blockIdx.x;
  const float* e = E + row * 2048;
  const int t = threadIdx.x;
  float4 a = ((const float4*)e)[t * 2];
  float4 b = ((const float4*)e)[t * 2 + 1];
  float f[8] = {a.x, a.y, a.z, a.w, b.x, b.y, b.z, b.w};
  float m = f[0];
#pragma unroll
  for (int j = 1; j < 8; j++) m = fmaxf(m, f[j]);
#pragma unroll
  for (int off = 32; off > 0; off >>= 1) m = fmaxf(m, __shfl_down(m, off));
  __shared__ float redm[4], reds[4];
  if ((t & 63) == 0) redm[t >> 6] = m;
  __syncthreads();
  m = fmaxf(fmaxf(redm[0], redm[1]), fmaxf(redm[2], redm[3]));
  float ex[8];
  float s = 0.f;
#pragma unroll
  for (int j = 0; j < 8; j++) { ex[j] = __expf(f[j] - m); s += ex[j]; }
#pragma unroll
  for (int off = 32; off > 0; off >>= 1) s += __shfl_down(s, off);
  if ((t & 63) == 0) reds[t >> 6] = s;
  __syncthreads();
  s = reds[0] + reds[1] + reds[2] + reds[3];
  float inv = 1.0f / s;
  int q1[8], q2[8];
#pragma unroll
  for (int j = 0; j < 8; j++)
    qsplit(ex[j] * inv, 1.0f / 127.0f, 127.0f, 16256.0f, q1[j], q2[j]);
  uint2 ua, ub;
  ua.x = pack4(q1[0], q1[1], q1[2], q1[3]); ua.y = pack4(q1[4], q1[5], q1[6], q1[7]);
  ub.x = pack4(q2[0], q2[1], q2[2], q2[3]); ub.y = pack4(q2[4], q2[5], q2[6], q2[7]);
  *(uint2*)(P1 + row * 2048 + t * 8) = ua;
  *(uint2*)(P2 + row * 2048 + t * 8) = ub;
}

// ---- GEMM1 (int8): E = c1*(A1.B1^T) + c2*(A1.B2^T + A2.B1^T) ----
// 128x128 tile, BK=64 (64B rows: byte-identical geometry/swizzle to proven bf16 BK=32).
__global__ __launch_bounds__(256) void gemm1_i8(
    const s8* __restrict__ A0, const s8* __restrict__ A1,
    const s8* __restrict__ B0, const s8* __restrict__ B1,
    float* __restrict__ C, int Kdim, int ldc, long sA, long sB, long sC) {
  __shared__ char lds[4 * 8192];
  const int tid = threadIdx.x;
  const int w = tid >> 6, l = tid & 63;
  const int bz = blockIdx.z;
  const int rowA = blockIdx.y * 128, rowB = blockIdx.x * 128;
  const s8* bases[4] = {A0 + bz * sA, A1 + bz * sA, B0 + bz * sB, B1 + bz * sB};
  const int rbase[4] = {rowA, rowA, rowB, rowB};
  const s8* gp[8];
  uint32_t lpo[8];
#pragma unroll
  for (int i = 0; i < 8; i++) {
    int gc = w * 8 + i;
    int buf = gc >> 3, c = gc & 7;
    int row = c * 16 + (l >> 2);
    int q = (l & 3) ^ ((row >> 1) & 3);
    gp[i] = bases[buf] + (size_t)(rbase[buf] + row) * Kdim + q * 16;
    lpo[i] = (uint32_t)(uintptr_t)(lds + buf * 8192 + c * 1024 + l * 16);
  }
  i32x4 acc1[4][4], acc2[4][4];
  const i32x4 zero = {0, 0, 0, 0};
#pragma unroll
  for (int mt = 0; mt < 4; mt++)
#pragma unroll
    for (int nt = 0; nt < 4; nt++) { acc1[mt][nt] = zero; acc2[mt][nt] = zero; }

  const int wm = w & 1, wn = w >> 1, q4 = l >> 4, rl = l & 15;
  for (int k0 = 0; k0 < Kdim; k0 += 64) {
    __syncthreads();
#pragma unroll
    for (int i = 0; i < 8; i++) gload_lds16(gp[i], lpo[i]);
#pragma unroll
    for (int i = 0; i < 8; i++) gp[i] += 64;
    __syncthreads();
    i32x4 af[2][4], bfr[2][4];
#pragma unroll
    for (int mt = 0; mt < 4; mt++) {
      int row = wm * 64 + mt * 16 + rl;
      int off = row * 64 + ((q4 ^ ((row >> 1) & 3)) << 4);
      af[0][mt] = *(const i32x4*)(lds + off);
      af[1][mt] = *(const i32x4*)(lds + 8192 + off);
    }
#pragma unroll
    for (int nt = 0; nt < 4; nt++) {
      int row = wn * 64 + nt * 16 + rl;
      int off = row * 64 + ((q4 ^ ((row >> 1) & 3)) << 4);
      bfr[0][nt] = *(const i32x4*)(lds + 16384 + off);
      bfr[1][nt] = *(const i32x4*)(lds + 24576 + off);
    }
#pragma unroll
    for (int mt = 0; mt < 4; mt++)
#pragma unroll
      for (int nt = 0; nt < 4; nt++) {
        acc1[mt][nt] = __builtin_amdgcn_mfma_i32_16x16x64_i8(af[0][mt], bfr[0][nt], acc1[mt][nt], 0, 0, 0);
        acc2[mt][nt] = __builtin_amdgcn_mfma_i32_16x16x64_i8(af[0][mt], bfr[1][nt], acc2[mt][nt], 0, 0, 0);
        acc2[mt][nt] = __builtin_amdgcn_mfma_i32_16x16x64_i8(af[1][mt], bfr[0][nt], acc2[mt][nt], 0, 0, 0);
      }
  }
  const float c1 = 64.0f / 16129.0f, c2 = c1 * (1.0f / 128.0f);
  float* Cb = C + (size_t)bz * sC + (size_t)rowA * ldc + rowB;
#pragma unroll
  for (int mt = 0; mt < 4; mt++)
#pragma unroll
    for (int nt = 0; nt < 4; nt++)
#pragma unroll
      for (int r = 0; r < 4; r++)
        Cb[(size_t)(wm * 64 + mt * 16 + q4 * 4 + r) * ldc + (wn * 64 + nt * 16 + rl)] =
            c1 * (float)acc1[mt][nt][r] + c2 * (float)acc2[mt][nt][r];
}

// ---- GEMM2 (int8): O = c1*(P1.KT1^T) + c2*(P1.KT2^T + P2.KT1^T) ----
// 128(m) x 64(n) tile, BK=64; grid 2x blocks vs round-2 to fix starvation.
__global__ __launch_bounds__(256) void gemm2_i8(
    const s8* __restrict__ A0, const s8* __restrict__ A1,
    const s8* __restrict__ B0, const s8* __restrict__ B1,
    float* __restrict__ C, int Kdim, int ldc, long sA, long sB, long sC) {
  __shared__ char lds[24576];  // P1@0 (8KB), P2@8192, K1@16384 (4KB), K2@20480
  const int tid = threadIdx.x;
  const int w = tid >> 6, l = tid & 63;
  const int bz = blockIdx.z;
  const int rowA = blockIdx.y * 128, rowB = blockIdx.x * 64;
  const s8* bases[4] = {A0 + bz * sA, A1 + bz * sA, B0 + bz * sB, B1 + bz * sB};
  const int rbase[4] = {rowA, rowA, rowB, rowB};
  const int bufoff[4] = {0, 8192, 16384, 20480};
  const s8* gp[6];
  uint32_t lpo[6];
#pragma unroll
  for (int i = 0; i < 6; i++) {
    int gc = w * 6 + i;
    int buf, c;
    if (gc < 8) { buf = 0; c = gc; }
    else if (gc < 16) { buf = 1; c = gc - 8; }
    else if (gc < 20) { buf = 2; c = gc - 16; }
    else { buf = 3; c = gc - 20; }
    int row = c * 16 + (l >> 2);
    int q = (l & 3) ^ ((row >> 1) & 3);
    gp[i] = bases[buf] + (size_t)(rbase[buf] + row) * Kdim + q * 16;
    lpo[i] = (uint32_t)(uintptr_t)(lds + bufoff[buf] + c * 1024 + l * 16);
  }
  i32x4 acc1[4][2], acc2[4][2];
  const i32x4 zero = {0, 0, 0, 0};
#pragma unroll
  for (int mt = 0; mt < 4; mt++)
#pragma unroll
    for (int nt = 0; nt < 2; nt++) { acc1[mt][nt] = zero; acc2[mt][nt] = zero; }

  const int wm = w & 1, wn = w >> 1, q4 = l >> 4, rl = l & 15;
  for (int k0 = 0; k0 < Kdim; k0 += 64) {
    __syncthreads();
#pragma unroll
    for (int i = 0; i < 6; i++) gload_lds16(gp[i], lpo[i]);
#pragma unroll
    for (int i = 0; i < 6; i++) gp[i] += 64;
    __syncthreads();
    i32x4 af[2][4], bfr[2][2];
#pragma unroll
    for (int mt = 0; mt < 4; mt++) {
      int row = wm * 64 + mt * 16 + rl;
      int off = row * 64 + ((q4 ^ ((row >> 1) & 3)) << 4);
      af[0][mt] = *(const i32x4*)(lds + off);
      af[1][mt] = *(const i32x4*)(lds + 8192 + off);
    }
#pragma unroll
    for (int nt = 0; nt < 2; nt++) {
      int row = wn * 32 + nt * 16 + rl;
      int off = row * 64 + ((q4 ^ ((row >> 1) & 3)) << 4);
      bfr[0][nt] = *(const i32x4*)(lds + 16384 + off);
      bfr[1][nt] = *(const i32x4*)(lds + 20480 + off);
    }
#pragma unroll
    for (int mt = 0; mt < 4; mt++)
#pragma unroll
      for (int nt = 0; nt < 2; nt++) {
        acc1[mt][nt] = __builtin_amdgcn_mfma_i32_16x16x64_i8(af[0][mt], bfr[0][nt], acc1[mt][nt], 0, 0, 0);
        acc2[mt][nt] = __builtin_amdgcn_mfma_i32_16x16x64_i8(af[0][mt], bfr[1][nt], acc2[mt][nt], 0, 0, 0);
        acc2[mt][nt] = __builtin_amdgcn_mfma_i32_16x16x64_i8(af[1][mt], bfr[0][nt], acc2[mt][nt], 0, 0, 0);
      }
  }
  const float c1 = 8.0f / 16129.0f, c2 = c1 * (1.0f / 128.0f);
  float* Cb = C + (size_t)bz * sC + (size_t)rowA * ldc + rowB;
#pragma unroll
  for (int mt = 0; mt < 4; mt++)
#pragma unroll
    for (int nt = 0; nt < 2; nt++)
#pragma unroll
      for (int r = 0; r < 4; r++)
        Cb[(size_t)(wm * 64 + mt * 16 + q4 * 4 + r) * ldc + (wn * 32 + nt * 16 + rl)] =
            c1 * (float)acc1[mt][nt][r] + c2 * (float)acc2[mt][nt][r];
}

extern "C" void kernel_launch(void* const* d_in, const int* in_sizes, int n_in,
                              void* d_out, int out_size, void* d_ws, size_t ws_size,
                              hipStream_t stream) {
  (void)in_sizes; (void)n_in; (void)out_size;
  const float* Q = (const float*)d_in[0];
  const float* K = (const float*)d_in[1];
  float* O = (float*)d_out;
  const int Btot = 8, Tq = 2048, Tk = 2048, D = 1024;
  // ws per batch: Q1,Q2,K1,K2,KT1,KT2 int8 (2MB each) + E fp32 16MB + P1,P2 int8 (4MB each) = 36MB
  const size_t perb = 36ull << 20;
  int NB = 8;
  while (NB > 1 && (size_t)NB * perb > ws_size) NB >>= 1;

  char* p = (char*)d_ws;
  const size_t qd = (size_t)NB * Tq * D;
  const size_t kd = (size_t)NB * Tk * D;
  const size_t ee = (size_t)NB * Tq * Tk;
  s8* Q1 = (s8*)p; p += qd;
  s8* Q2 = (s8*)p; p += qd;
  s8* K1 = (s8*)p; p += kd;
  s8* K2 = (s8*)p; p += kd;
  s8* KT1 = (s8*)p; p += kd;
  s8* KT2 = (s8*)p; p += kd;
  float* E = (float*)p; p += ee * 4;
  s8* P1 = (s8*)p; p += ee;
  s8* P2 = (s8*)p; p += ee;

  for (int c = 0; c < Btot / NB; c++) {
    const float* Qc = Q + (size_t)c * qd;
    const float* Kc = K + (size_t)c * kd;
    float* Oc = O + (size_t)c * qd;
    cvt_q_i8<<<dim3(NB * 1024), 256, 0, stream>>>(Qc, Q1, Q2);
    cvt_k_i8<<<dim3(32, 32, NB), 256, 0, stream>>>(Kc, K1, K2, KT1, KT2);
    gemm1_i8<<<dim3(16, 16, NB), 256, 0, stream>>>(
        Q1, Q2, K1, K2, E, 1024, 2048, (long)Tq * D, (long)Tk * D, (long)Tq * Tk);
    softmax_i8<<<dim3(NB * Tq), 256, 0, stream>>>(E, P1, P2);
    gemm2_i8<<<dim3(16, 16, NB), 256, 0, stream>>>(
        P1, P2, KT1, KT2, Oc, 2048, 1024, (long)Tq * Tk, (long)D * Tk, (long)Tq * D);
  }
}